// Round 1
// baseline (589.870 us; speedup 1.0000x reference)
//
#include <hip/hip_runtime.h>
#include <cstdint>
#include <cstddef>

using u16 = unsigned short;
using u32 = unsigned int;

#define DI __device__ __forceinline__

typedef __attribute__((ext_vector_type(8))) short bf16x8;
typedef __attribute__((ext_vector_type(4))) float f32x4;

// bf16 <-> f32 helpers (bit math). Intermediates stored bf16 in ws.
DI float bfu2f(u16 u) { return __uint_as_float(((u32)u) << 16); }
DI u16 f2bu(float f) {  // round-to-nearest-even, finite inputs only
    u32 x = __float_as_uint(f);
    return (u16)((x + 0x7fffu + ((x >> 16) & 1u)) >> 16);
}
DI u32 pk2(float a, float b) { return (u32)f2bu(a) | ((u32)f2bu(b) << 16); }

constexpr int CIN = 512;
constexpr int HW  = 4096;              // 64*64
constexpr size_t PLANE = 16777216ull;  // 8*512*4096 elements per output tensor

// ================= MFMA projection GEMM =================
// Out[M x 32768] = Wcat[M x 512] @ X[512 x (b,4096)] + bias; bf16 out.
// Row routing: [0,n0r) -> w0/o0, [n0r,n0r+n1r) -> w1/o1, rest -> w2/o2.
// grid (nTiles=256, mTiles=M/128), block 256 (4 waves), 128x128 tile, BK=32.
__global__ __launch_bounds__(256) void proj_mfma(
    const float* __restrict__ X,
    const float* __restrict__ w0, const float* __restrict__ b0, int n0r,
    const float* __restrict__ w1, const float* __restrict__ b1, int n1r,
    const float* __restrict__ w2, const float* __restrict__ b2,
    u16* __restrict__ o0, u16* __restrict__ o1, u16* __restrict__ o2,
    int o0c, int o1c, int o2c)
{
    __shared__ u16 Wlds[128][40];   // [m][k], rows 80 B (16B-aligned b128)
    __shared__ u16 Xlds[32][136];   // [k][n], rows 272 B (2-way-max banks)
    const int tid = threadIdx.x;
    const int m0  = blockIdx.y * 128;
    const int n0g = blockIdx.x * 128;
    const int b    = n0g >> 12;
    const int col0 = n0g & 4095;
    const float* Xb = X + (size_t)b * CIN * HW;

    // staging coords
    const int ml = tid >> 1, wk0 = (tid & 1) * 16;   // W: 16 f32/thread
    const int xk = tid >> 3, xnb = (tid & 7) * 16;   // X: 16 f32/thread
    const int mrow = m0 + ml;
    const float* wr = (mrow < n0r) ? w0 + (size_t)mrow * CIN
                    : (mrow < n0r + n1r) ? w1 + (size_t)(mrow - n0r) * CIN
                    : w2 + (size_t)(mrow - n0r - n1r) * CIN;

    const int lane = tid & 63, wv = tid >> 6;
    const int wm = (wv & 1) * 64, wn = (wv >> 1) * 64;
    const int lr = lane & 15, lq = lane >> 4;

    f32x4 acc[4][4] = {};
    for (int kt = 0; kt < CIN; kt += 32) {
        // stage W (f32 -> bf16)
        {
            const float* p = wr + kt + wk0;
            float4 f0 = *(const float4*)(p);
            float4 f1 = *(const float4*)(p + 4);
            float4 f2 = *(const float4*)(p + 8);
            float4 f3 = *(const float4*)(p + 12);
            uint4 u0 = { pk2(f0.x, f0.y), pk2(f0.z, f0.w), pk2(f1.x, f1.y), pk2(f1.z, f1.w) };
            uint4 u1 = { pk2(f2.x, f2.y), pk2(f2.z, f2.w), pk2(f3.x, f3.y), pk2(f3.z, f3.w) };
            *(uint4*)&Wlds[ml][wk0]     = u0;
            *(uint4*)&Wlds[ml][wk0 + 8] = u1;
        }
        // stage X (f32 -> bf16), natural [k][n]
        {
            const float* p = Xb + (size_t)(kt + xk) * HW + col0 + xnb;
            float4 f0 = *(const float4*)(p);
            float4 f1 = *(const float4*)(p + 4);
            float4 f2 = *(const float4*)(p + 8);
            float4 f3 = *(const float4*)(p + 12);
            uint4 u0 = { pk2(f0.x, f0.y), pk2(f0.z, f0.w), pk2(f1.x, f1.y), pk2(f1.z, f1.w) };
            uint4 u1 = { pk2(f2.x, f2.y), pk2(f2.z, f2.w), pk2(f3.x, f3.y), pk2(f3.z, f3.w) };
            *(uint4*)&Xlds[xk][xnb]     = u0;
            *(uint4*)&Xlds[xk][xnb + 8] = u1;
        }
        __syncthreads();
        // A-frags: lane holds A[m=lr][k=lq*8+j] -> b128 from Wlds
        bf16x8 a[4];
        #pragma unroll
        for (int i = 0; i < 4; i++)
            a[i] = *(const bf16x8*)&Wlds[wm + i * 16 + lr][lq * 8];
        // B-frags: lane holds B[k=lq*8+j][n=lr] -> 8 scalar reads from Xlds
        #pragma unroll
        for (int j = 0; j < 4; j++) {
            bf16x8 bv;
            const int nn = wn + j * 16 + lr;
            #pragma unroll
            for (int jj = 0; jj < 8; jj++) bv[jj] = (short)Xlds[lq * 8 + jj][nn];
            #pragma unroll
            for (int i = 0; i < 4; i++)
                acc[i][j] = __builtin_amdgcn_mfma_f32_16x16x32_bf16(a[i], bv, acc[i][j], 0, 0, 0);
        }
        __syncthreads();
    }
    // epilogue: D row = lq*4 + r, col = lr. Route per 16-row frag (uniform).
    #pragma unroll
    for (int i = 0; i < 4; i++) {
        const int mbase = m0 + wm + i * 16;
        const float* bp; u16* op; int ch0, cc;
        if (mbase < n0r)             { bp = b0; op = o0; ch0 = mbase;             cc = o0c; }
        else if (mbase < n0r + n1r)  { bp = b1; op = o1; ch0 = mbase - n0r;       cc = o1c; }
        else                         { bp = b2; op = o2; ch0 = mbase - n0r - n1r; cc = o2c; }
        #pragma unroll
        for (int r = 0; r < 4; r++) {
            const int ch = ch0 + lq * 4 + r;
            const float bias = bp[ch];
            #pragma unroll
            for (int j = 0; j < 4; j++) {
                const int colx = col0 + wn + j * 16 + lr;
                op[((size_t)b * cc + ch) * HW + colx] = f2bu(acc[i][j][r] + bias);
            }
        }
    }
}

// ============== 64x64 last-two-dims transpose (bf16 -> bf16) ==============
__global__ __launch_bounds__(256) void transpose64_bb(
    const u16* __restrict__ src, u16* __restrict__ dst)
{
    __shared__ u16 t[64][65];
    const size_t s = blockIdx.x;
    const u16* sp = src + s * 4096;
    u16* dp = dst + s * 4096;
    const int tid = threadIdx.x;
    #pragma unroll
    for (int i = 0; i < 16; i++) { int idx = tid + 256 * i; t[idx >> 6][idx & 63] = sp[idx]; }
    __syncthreads();
    #pragma unroll
    for (int i = 0; i < 16; i++) { int idx = tid + 256 * i; dp[idx] = t[idx & 63][idx >> 6]; }
}

// ============== in-place per-slice 64x64 bf16 transpose ==============
__global__ __launch_bounds__(256) void transpose64_bb_inplace(u16* __restrict__ d)
{
    __shared__ u16 t[64][65];
    u16* p = d + (size_t)blockIdx.x * 4096;
    const int tid = threadIdx.x;
    #pragma unroll
    for (int i = 0; i < 16; i++) { int idx = tid + 256 * i; t[idx >> 6][idx & 63] = p[idx]; }
    __syncthreads();
    #pragma unroll
    for (int i = 0; i < 16; i++) { int idx = tid + 256 * i; p[idx] = t[idx & 63][idx >> 6]; }
}

// ======================= energies =======================
// e layout: (b,h,w,128) fp32. [0:64) = energy_H, [64:128) = energy_W.
__global__ __launch_bounds__(256) void energy_h(
    const u16* __restrict__ qT, const u16* __restrict__ kT, float* __restrict__ e)
{
    __shared__ float Qs[64][68];  // [c][h]
    __shared__ float Ks[64][68];  // [c][H']
    const int w = blockIdx.x, b = blockIdx.y;
    const int tid = threadIdx.x;
    const size_t base = (size_t)b * 64 * HW + (size_t)w * 64;  // qT[b,c,w,h]
    #pragma unroll
    for (int i = 0; i < 16; i++) {
        int idx = tid + 256 * i;
        int c = idx >> 6, x = idx & 63;
        Qs[c][x] = bfu2f(qT[base + (size_t)c * HW + x]);
        Ks[c][x] = bfu2f(kT[base + (size_t)c * HW + x]);
    }
    __syncthreads();
    const int tx = tid & 15, ty = tid >> 4;  // tx -> h, ty -> H'
    float acc[4][4] = {};
    #pragma unroll 8
    for (int c = 0; c < 64; c++) {
        float4 qv = *reinterpret_cast<const float4*>(&Qs[c][tx * 4]);
        float4 kv = *reinterpret_cast<const float4*>(&Ks[c][ty * 4]);
        float a[4] = {qv.x, qv.y, qv.z, qv.w};
        float d[4] = {kv.x, kv.y, kv.z, kv.w};
        #pragma unroll
        for (int i = 0; i < 4; i++)
            #pragma unroll
            for (int j = 0; j < 4; j++) acc[i][j] += a[i] * d[j];
    }
    #pragma unroll
    for (int i = 0; i < 4; i++) {
        float4 v = make_float4(acc[i][0], acc[i][1], acc[i][2], acc[i][3]);
        *reinterpret_cast<float4*>(e + ((size_t)(b * 64 + tx * 4 + i) * 64 + w) * 128 + ty * 4) = v;
    }
}

__global__ __launch_bounds__(256) void energy_w(
    const u16* __restrict__ q, const u16* __restrict__ k, float* __restrict__ e)
{
    __shared__ float Qs[64][68];  // [c][w]
    __shared__ float Ks[64][68];  // [c][W']
    const int h = blockIdx.x, b = blockIdx.y;
    const int tid = threadIdx.x;
    const size_t base = (size_t)b * 64 * HW + (size_t)h * 64;  // q[b,c,h,w]
    #pragma unroll
    for (int i = 0; i < 16; i++) {
        int idx = tid + 256 * i;
        int c = idx >> 6, x = idx & 63;
        Qs[c][x] = bfu2f(q[base + (size_t)c * HW + x]);
        Ks[c][x] = bfu2f(k[base + (size_t)c * HW + x]);
    }
    __syncthreads();
    const int tx = tid & 15, ty = tid >> 4;  // tx -> w, ty -> W'
    float acc[4][4] = {};
    #pragma unroll 8
    for (int c = 0; c < 64; c++) {
        float4 qv = *reinterpret_cast<const float4*>(&Qs[c][tx * 4]);
        float4 kv = *reinterpret_cast<const float4*>(&Ks[c][ty * 4]);
        float a[4] = {qv.x, qv.y, qv.z, qv.w};
        float d[4] = {kv.x, kv.y, kv.z, kv.w};
        #pragma unroll
        for (int i = 0; i < 4; i++)
            #pragma unroll
            for (int j = 0; j < 4; j++) acc[i][j] += a[i] * d[j];
    }
    #pragma unroll
    for (int i = 0; i < 4; i++) {
        float4 v = make_float4(acc[i][0], acc[i][1], acc[i][2], acc[i][3]);
        *reinterpret_cast<float4*>(e + ((size_t)(b * 64 + h) * 64 + tx * 4 + i) * 128 + 64 + ty * 4) = v;
    }
}

// ============ softmax over 128, f32 in -> bf16 out ============
__global__ __launch_bounds__(256) void softmax128_bf(
    const float* __restrict__ e, u16* __restrict__ attb)
{
    const int pos = blockIdx.x * 4 + (threadIdx.x >> 6);
    const int l = threadIdx.x & 63;
    const float* p = e + (size_t)pos * 128;
    float v0 = p[l], v1 = p[l + 64];
    float m = fmaxf(v0, v1);
    #pragma unroll
    for (int o = 32; o > 0; o >>= 1) m = fmaxf(m, __shfl_xor(m, o, 64));
    float e0 = __expf(v0 - m), e1 = __expf(v1 - m);
    float s = e0 + e1;
    #pragma unroll
    for (int o = 32; o > 0; o >>= 1) s += __shfl_xor(s, o, 64);
    float inv = 1.0f / s;
    u16* q = attb + (size_t)pos * 128;
    q[l] = f2bu(e0 * inv);
    q[l + 64] = f2bu(e1 * inv);
}

// ======================= H-aggregation (MFMA, in-place over vT) ===========
// P[b,c,w,h] = sum_H' vT[b,c,w,H'] * attH[b,h,w,H']   (bf16 out, written over
// the vT rows the block itself read — all loads are in registers before the
// barrier, so the overwrite is safe; blocks touch disjoint (b,c-range,w) rows).
// grid (mt=8, w=64, b=8), block 256 (4 waves). mt 0-3 -> a-side, 4-7 -> b-side.
__global__ __launch_bounds__(256) void agg_h_mfma(
    const u16* __restrict__ vTa, const u16* __restrict__ vTb,
    const u16* __restrict__ attb, u16* __restrict__ Pa, u16* __restrict__ Pb)
{
    const int mt = blockIdx.x, w = blockIdx.y, b = blockIdx.z;
    const u16* vT = (mt < 4) ? vTa : vTb;
    u16*       P  = (mt < 4) ? Pa  : Pb;
    const int c0 = (mt & 3) * 128;
    const int lane = threadIdx.x & 63, wv = threadIdx.x >> 6;
    const int wm = (wv & 1) * 64, wn = (wv >> 1) * 32;
    const int lr = lane & 15, lq = lane >> 4;
    const u16* va = vT + ((size_t)(b * 512 + c0) * 64 + w) * 64;          // + c*4096 + H'
    const u16* ab = attb + ((size_t)b * 4096 + w) * 128;                  // + h*8192 + H'
    bf16x8 afr[2][4], bfr[2][2];
    #pragma unroll
    for (int kt = 0; kt < 2; kt++) {
        const int k0 = kt * 32 + lq * 8;
        #pragma unroll
        for (int i = 0; i < 4; i++)
            afr[kt][i] = *(const bf16x8*)(va + (size_t)(wm + i * 16 + lr) * 4096 + k0);
        #pragma unroll
        for (int j = 0; j < 2; j++)
            bfr[kt][j] = *(const bf16x8*)(ab + (size_t)(wn + j * 16 + lr) * 8192 + k0);
    }
    __syncthreads();  // all vT reads complete (vmcnt drained) before in-place stores
    f32x4 acc[4][2] = {};
    #pragma unroll
    for (int kt = 0; kt < 2; kt++)
        #pragma unroll
        for (int j = 0; j < 2; j++)
            #pragma unroll
            for (int i = 0; i < 4; i++)
                acc[i][j] = __builtin_amdgcn_mfma_f32_16x16x32_bf16(afr[kt][i], bfr[kt][j], acc[i][j], 0, 0, 0);
    // D: row(c within 16-tile) = lq*4+r, col(h) = lr
    #pragma unroll
    for (int i = 0; i < 4; i++)
        #pragma unroll
        for (int j = 0; j < 2; j++) {
            u16* pp = P + ((size_t)(b * 512 + c0 + wm + i * 16 + lq * 4) * 64 + w) * 64 + wn + j * 16 + lr;
            #pragma unroll
            for (int r = 0; r < 4; r++) pp[(size_t)r * 4096] = f2bu(acc[i][j][r]);
        }
}

// ======================= W-aggregation (MFMA) + epilogue ==================
// OutW[c,w] (fixed b,h) = sum_W' v[b,c,h,W'] * attW[b,h,w,W']
// y = g*(P + OutW) + x   (P now in (b,c,h,w) bf16, x/y f32)
__global__ __launch_bounds__(256) void agg_w_mfma(
    const u16* __restrict__ v2, const u16* __restrict__ v1,
    const u16* __restrict__ P2, const u16* __restrict__ P1,
    const u16* __restrict__ attb,
    const float* __restrict__ x2, const float* __restrict__ x1,
    const float* __restrict__ gptr, float* __restrict__ out)
{
    const int mt = blockIdx.x, h = blockIdx.y, b = blockIdx.z;
    const u16* v = (mt < 4) ? v2 : v1;
    const u16* P = (mt < 4) ? P2 : P1;
    const float* x = (mt < 4) ? x2 : x1;
    float* y = out + ((mt < 4) ? 0 : PLANE);
    const int c0 = (mt & 3) * 128;
    const int lane = threadIdx.x & 63, wv = threadIdx.x >> 6;
    const int wm = (wv & 1) * 64, wn = (wv >> 1) * 32;
    const int lr = lane & 15, lq = lane >> 4;
    const u16* vb = v + (size_t)(b * 512 + c0) * 4096 + h * 64;           // + c*4096 + W'
    const u16* ab = attb + ((size_t)(b * 64 + h) * 64) * 128 + 64;        // + w*128 + W'
    f32x4 acc[4][2] = {};
    #pragma unroll
    for (int kt = 0; kt < 2; kt++) {
        const int k0 = kt * 32 + lq * 8;
        bf16x8 afr[4];
        #pragma unroll
        for (int i = 0; i < 4; i++)
            afr[i] = *(const bf16x8*)(vb + (size_t)(wm + i * 16 + lr) * 4096 + k0);
        #pragma unroll
        for (int j = 0; j < 2; j++) {
            bf16x8 bfr = *(const bf16x8*)(ab + (size_t)(wn + j * 16 + lr) * 128 + k0);
            #pragma unroll
            for (int i = 0; i < 4; i++)
                acc[i][j] = __builtin_amdgcn_mfma_f32_16x16x32_bf16(afr[i], bfr, acc[i][j], 0, 0, 0);
        }
    }
    const float g = gptr[0];
    #pragma unroll
    for (int i = 0; i < 4; i++)
        #pragma unroll
        for (int j = 0; j < 2; j++) {
            size_t off = (size_t)(b * 512 + c0 + wm + i * 16 + lq * 4) * 4096
                       + (size_t)h * 64 + wn + j * 16 + lr;
            #pragma unroll
            for (int r = 0; r < 4; r++) {
                size_t o = off + (size_t)r * 4096;
                y[o] = g * (bfu2f(P[o]) + acc[i][j][r]) + x[o];
            }
        }
}

// ======================= host =======================
extern "C" void kernel_launch(void* const* d_in, const int* in_sizes, int n_in,
                              void* d_out, int out_size, void* d_ws, size_t ws_size,
                              hipStream_t stream)
{
    (void)in_sizes; (void)n_in; (void)out_size; (void)ws_size;
    const float* x2  = (const float*)d_in[0];
    const float* x1  = (const float*)d_in[1];
    const float* q_w = (const float*)d_in[2];
    const float* q_b = (const float*)d_in[3];
    const float* k_w = (const float*)d_in[4];
    const float* k_b = (const float*)d_in[5];
    const float* v_w = (const float*)d_in[6];
    const float* v_b = (const float*)d_in[7];
    const float* gm  = (const float*)d_in[8];

    // ws (MiB): v2 0-32 | v1 32-64 | attb 64-72 |
    //   scratch (dead after softmax): q 72-76 | k 76-80 | qT 80-84 | kT 84-88 | e 88-104
    //   vT2/P2 72-104, vT1/P1 104-136 (written after softmax; overlay scratch)
    // Total: 136 MiB.
    char* ws = (char*)d_ws;
    u16*   v2   = (u16*)(ws);
    u16*   v1   = (u16*)(ws + ((size_t)32  << 20));
    u16*   attb = (u16*)(ws + ((size_t)64  << 20));
    u16*   q    = (u16*)(ws + ((size_t)72  << 20));
    u16*   k    = (u16*)(ws + ((size_t)76  << 20));
    u16*   qT   = (u16*)(ws + ((size_t)80  << 20));
    u16*   kT   = (u16*)(ws + ((size_t)84  << 20));
    float* e    = (float*)(ws + ((size_t)88 << 20));
    u16*   vT2  = (u16*)(ws + ((size_t)72  << 20));  // overlays q..e (dead by then)
    u16*   vT1  = (u16*)(ws + ((size_t)104 << 20));
    float* out = (float*)d_out;

    dim3 blk(256);
    // fused q/k/v2 projection from x2 (M=640), v1 from x1 (M=512)
    proj_mfma<<<dim3(256, 5), blk, 0, stream>>>(x2, q_w, q_b, 64, k_w, k_b, 64,
                                                v_w, v_b, q, k, v2, 64, 64, 512);
    proj_mfma<<<dim3(256, 4), blk, 0, stream>>>(x1, v_w, v_b, 0, v_w, v_b, 0,
                                                v_w, v_b, q, k, v1, 64, 64, 512);
    transpose64_bb<<<1024, blk, 0, stream>>>(q, qT);        // q+k -> qT+kT
    energy_h<<<dim3(64, 8), blk, 0, stream>>>(qT, kT, e);
    energy_w<<<dim3(64, 8), blk, 0, stream>>>(q, k, e);
    softmax128_bf<<<8192, blk, 0, stream>>>(e, attb);       // e dead after this
    transpose64_bb<<<8192, blk, 0, stream>>>(v2, vT2);      // v2+v1 -> vT2+vT1
    agg_h_mfma<<<dim3(8, 64, 8), blk, 0, stream>>>(vT2, vT1, attb, vT2, vT1); // P over vT
    transpose64_bb_inplace<<<8192, blk, 0, stream>>>(vT2);  // P -> (b,c,h,w)
    agg_w_mfma<<<dim3(8, 64, 8), blk, 0, stream>>>(v2, v1, vT2, vT1, attb,
                                                   x2, x1, gm, out);
}

// Round 2
// 498.500 us; speedup vs baseline: 1.1833x; 1.1833x over previous
//
#include <hip/hip_runtime.h>
#include <cstdint>
#include <cstddef>

using u16 = unsigned short;
using u32 = unsigned int;

#define DI __device__ __forceinline__

typedef __attribute__((ext_vector_type(8))) short bf16x8;
typedef __attribute__((ext_vector_type(4))) float f32x4;

// bf16 <-> f32 helpers (bit math). Intermediates stored bf16 in ws.
DI float bfu2f(u16 u) { return __uint_as_float(((u32)u) << 16); }
DI u16 f2bu(float f) {  // round-to-nearest-even, finite inputs only
    u32 x = __float_as_uint(f);
    return (u16)((x + 0x7fffu + ((x >> 16) & 1u)) >> 16);
}
DI u32 pk2(float a, float b) { return (u32)f2bu(a) | ((u32)f2bu(b) << 16); }

constexpr int CIN = 512;
constexpr int HW  = 4096;              // 64*64
constexpr size_t PLANE = 16777216ull;  // 8*512*4096 elements per output tensor

// ================= MFMA projection GEMM =================
// Out[M x 32768] = Wcat[M x 512] @ X[512 x (b,4096)] + bias; bf16 out.
// Row routing: [0,n0r) -> w0/o0, [n0r,n0r+n1r) -> w1/o1, rest -> w2/o2.
// grid (nTiles=256, mTiles=M/128), block 256 (4 waves), 128x128 tile, BK=32.
__global__ __launch_bounds__(256) void proj_mfma(
    const float* __restrict__ X,
    const float* __restrict__ w0, const float* __restrict__ b0, int n0r,
    const float* __restrict__ w1, const float* __restrict__ b1, int n1r,
    const float* __restrict__ w2, const float* __restrict__ b2,
    u16* __restrict__ o0, u16* __restrict__ o1, u16* __restrict__ o2,
    int o0c, int o1c, int o2c)
{
    __shared__ u16 Wlds[128][40];   // [m][k], rows 80 B (16B-aligned b128)
    __shared__ u16 Xlds[32][136];   // [k][n], rows 272 B (2-way-max banks)
    const int tid = threadIdx.x;
    const int m0  = blockIdx.y * 128;
    const int n0g = blockIdx.x * 128;
    const int b    = n0g >> 12;
    const int col0 = n0g & 4095;
    const float* Xb = X + (size_t)b * CIN * HW;

    // staging coords
    const int ml = tid >> 1, wk0 = (tid & 1) * 16;   // W: 16 f32/thread
    const int xk = tid >> 3, xnb = (tid & 7) * 16;   // X: 16 f32/thread
    const int mrow = m0 + ml;
    const float* wr = (mrow < n0r) ? w0 + (size_t)mrow * CIN
                    : (mrow < n0r + n1r) ? w1 + (size_t)(mrow - n0r) * CIN
                    : w2 + (size_t)(mrow - n0r - n1r) * CIN;

    const int lane = tid & 63, wv = tid >> 6;
    const int wm = (wv & 1) * 64, wn = (wv >> 1) * 64;
    const int lr = lane & 15, lq = lane >> 4;

    f32x4 acc[4][4] = {};
    for (int kt = 0; kt < CIN; kt += 32) {
        // stage W (f32 -> bf16)
        {
            const float* p = wr + kt + wk0;
            float4 f0 = *(const float4*)(p);
            float4 f1 = *(const float4*)(p + 4);
            float4 f2 = *(const float4*)(p + 8);
            float4 f3 = *(const float4*)(p + 12);
            uint4 u0 = { pk2(f0.x, f0.y), pk2(f0.z, f0.w), pk2(f1.x, f1.y), pk2(f1.z, f1.w) };
            uint4 u1 = { pk2(f2.x, f2.y), pk2(f2.z, f2.w), pk2(f3.x, f3.y), pk2(f3.z, f3.w) };
            *(uint4*)&Wlds[ml][wk0]     = u0;
            *(uint4*)&Wlds[ml][wk0 + 8] = u1;
        }
        // stage X (f32 -> bf16), natural [k][n]
        {
            const float* p = Xb + (size_t)(kt + xk) * HW + col0 + xnb;
            float4 f0 = *(const float4*)(p);
            float4 f1 = *(const float4*)(p + 4);
            float4 f2 = *(const float4*)(p + 8);
            float4 f3 = *(const float4*)(p + 12);
            uint4 u0 = { pk2(f0.x, f0.y), pk2(f0.z, f0.w), pk2(f1.x, f1.y), pk2(f1.z, f1.w) };
            uint4 u1 = { pk2(f2.x, f2.y), pk2(f2.z, f2.w), pk2(f3.x, f3.y), pk2(f3.z, f3.w) };
            *(uint4*)&Xlds[xk][xnb]     = u0;
            *(uint4*)&Xlds[xk][xnb + 8] = u1;
        }
        __syncthreads();
        // A-frags: lane holds A[m=lr][k=lq*8+j] -> b128 from Wlds
        bf16x8 a[4];
        #pragma unroll
        for (int i = 0; i < 4; i++)
            a[i] = *(const bf16x8*)&Wlds[wm + i * 16 + lr][lq * 8];
        // B-frags: lane holds B[k=lq*8+j][n=lr] -> 8 scalar reads from Xlds
        #pragma unroll
        for (int j = 0; j < 4; j++) {
            bf16x8 bv;
            const int nn = wn + j * 16 + lr;
            #pragma unroll
            for (int jj = 0; jj < 8; jj++) bv[jj] = (short)Xlds[lq * 8 + jj][nn];
            #pragma unroll
            for (int i = 0; i < 4; i++)
                acc[i][j] = __builtin_amdgcn_mfma_f32_16x16x32_bf16(a[i], bv, acc[i][j], 0, 0, 0);
        }
        __syncthreads();
    }
    // epilogue: D row = lq*4 + r, col = lr. Route per 16-row frag (uniform).
    #pragma unroll
    for (int i = 0; i < 4; i++) {
        const int mbase = m0 + wm + i * 16;
        const float* bp; u16* op; int ch0, cc;
        if (mbase < n0r)             { bp = b0; op = o0; ch0 = mbase;             cc = o0c; }
        else if (mbase < n0r + n1r)  { bp = b1; op = o1; ch0 = mbase - n0r;       cc = o1c; }
        else                         { bp = b2; op = o2; ch0 = mbase - n0r - n1r; cc = o2c; }
        #pragma unroll
        for (int r = 0; r < 4; r++) {
            const int ch = ch0 + lq * 4 + r;
            const float bias = bp[ch];
            #pragma unroll
            for (int j = 0; j < 4; j++) {
                const int colx = col0 + wn + j * 16 + lr;
                op[((size_t)b * cc + ch) * HW + colx] = f2bu(acc[i][j][r] + bias);
            }
        }
    }
}

// ============== 64x64 last-two-dims transpose (bf16 -> bf16) ==============
__global__ __launch_bounds__(256) void transpose64_bb(
    const u16* __restrict__ src, u16* __restrict__ dst)
{
    __shared__ u16 t[64][65];
    const size_t s = blockIdx.x;
    const u16* sp = src + s * 4096;
    u16* dp = dst + s * 4096;
    const int tid = threadIdx.x;
    #pragma unroll
    for (int i = 0; i < 16; i++) { int idx = tid + 256 * i; t[idx >> 6][idx & 63] = sp[idx]; }
    __syncthreads();
    #pragma unroll
    for (int i = 0; i < 16; i++) { int idx = tid + 256 * i; dp[idx] = t[idx & 63][idx >> 6]; }
}

// ============== in-place per-slice 64x64 bf16 transpose ==============
__global__ __launch_bounds__(256) void transpose64_bb_inplace(u16* __restrict__ d)
{
    __shared__ u16 t[64][65];
    u16* p = d + (size_t)blockIdx.x * 4096;
    const int tid = threadIdx.x;
    #pragma unroll
    for (int i = 0; i < 16; i++) { int idx = tid + 256 * i; t[idx >> 6][idx & 63] = p[idx]; }
    __syncthreads();
    #pragma unroll
    for (int i = 0; i < 16; i++) { int idx = tid + 256 * i; p[idx] = t[idx & 63][idx >> 6]; }
}

// ======================= energies =======================
// e layout: (b,h,w,128) fp32. [0:64) = energy_H, [64:128) = energy_W.
__global__ __launch_bounds__(256) void energy_h(
    const u16* __restrict__ qT, const u16* __restrict__ kT, float* __restrict__ e)
{
    __shared__ float Qs[64][68];  // [c][h]
    __shared__ float Ks[64][68];  // [c][H']
    const int w = blockIdx.x, b = blockIdx.y;
    const int tid = threadIdx.x;
    const size_t base = (size_t)b * 64 * HW + (size_t)w * 64;  // qT[b,c,w,h]
    #pragma unroll
    for (int i = 0; i < 16; i++) {
        int idx = tid + 256 * i;
        int c = idx >> 6, x = idx & 63;
        Qs[c][x] = bfu2f(qT[base + (size_t)c * HW + x]);
        Ks[c][x] = bfu2f(kT[base + (size_t)c * HW + x]);
    }
    __syncthreads();
    const int tx = tid & 15, ty = tid >> 4;  // tx -> h, ty -> H'
    float acc[4][4] = {};
    #pragma unroll 8
    for (int c = 0; c < 64; c++) {
        float4 qv = *reinterpret_cast<const float4*>(&Qs[c][tx * 4]);
        float4 kv = *reinterpret_cast<const float4*>(&Ks[c][ty * 4]);
        float a[4] = {qv.x, qv.y, qv.z, qv.w};
        float d[4] = {kv.x, kv.y, kv.z, kv.w};
        #pragma unroll
        for (int i = 0; i < 4; i++)
            #pragma unroll
            for (int j = 0; j < 4; j++) acc[i][j] += a[i] * d[j];
    }
    #pragma unroll
    for (int i = 0; i < 4; i++) {
        float4 v = make_float4(acc[i][0], acc[i][1], acc[i][2], acc[i][3]);
        *reinterpret_cast<float4*>(e + ((size_t)(b * 64 + tx * 4 + i) * 64 + w) * 128 + ty * 4) = v;
    }
}

__global__ __launch_bounds__(256) void energy_w(
    const u16* __restrict__ q, const u16* __restrict__ k, float* __restrict__ e)
{
    __shared__ float Qs[64][68];  // [c][w]
    __shared__ float Ks[64][68];  // [c][W']
    const int h = blockIdx.x, b = blockIdx.y;
    const int tid = threadIdx.x;
    const size_t base = (size_t)b * 64 * HW + (size_t)h * 64;  // q[b,c,h,w]
    #pragma unroll
    for (int i = 0; i < 16; i++) {
        int idx = tid + 256 * i;
        int c = idx >> 6, x = idx & 63;
        Qs[c][x] = bfu2f(q[base + (size_t)c * HW + x]);
        Ks[c][x] = bfu2f(k[base + (size_t)c * HW + x]);
    }
    __syncthreads();
    const int tx = tid & 15, ty = tid >> 4;  // tx -> w, ty -> W'
    float acc[4][4] = {};
    #pragma unroll 8
    for (int c = 0; c < 64; c++) {
        float4 qv = *reinterpret_cast<const float4*>(&Qs[c][tx * 4]);
        float4 kv = *reinterpret_cast<const float4*>(&Ks[c][ty * 4]);
        float a[4] = {qv.x, qv.y, qv.z, qv.w};
        float d[4] = {kv.x, kv.y, kv.z, kv.w};
        #pragma unroll
        for (int i = 0; i < 4; i++)
            #pragma unroll
            for (int j = 0; j < 4; j++) acc[i][j] += a[i] * d[j];
    }
    #pragma unroll
    for (int i = 0; i < 4; i++) {
        float4 v = make_float4(acc[i][0], acc[i][1], acc[i][2], acc[i][3]);
        *reinterpret_cast<float4*>(e + ((size_t)(b * 64 + h) * 64 + tx * 4 + i) * 128 + 64 + ty * 4) = v;
    }
}

// ============ softmax over 128, f32 in -> bf16 out ============
__global__ __launch_bounds__(256) void softmax128_bf(
    const float* __restrict__ e, u16* __restrict__ attb)
{
    const int pos = blockIdx.x * 4 + (threadIdx.x >> 6);
    const int l = threadIdx.x & 63;
    const float* p = e + (size_t)pos * 128;
    float v0 = p[l], v1 = p[l + 64];
    float m = fmaxf(v0, v1);
    #pragma unroll
    for (int o = 32; o > 0; o >>= 1) m = fmaxf(m, __shfl_xor(m, o, 64));
    float e0 = __expf(v0 - m), e1 = __expf(v1 - m);
    float s = e0 + e1;
    #pragma unroll
    for (int o = 32; o > 0; o >>= 1) s += __shfl_xor(s, o, 64);
    float inv = 1.0f / s;
    u16* q = attb + (size_t)pos * 128;
    q[l] = f2bu(e0 * inv);
    q[l + 64] = f2bu(e1 * inv);
}

// ======================= H-aggregation (MFMA, LDS-staged, in-place) =======
// P[b,c,w,h] = sum_H' vT[b,c,w,H'] * attH[b,h,w,H']  (bf16 out, written over
// the vT rows the block itself read; all reads land in LDS before compute,
// blocks touch disjoint (b,c-range,w) rows -> in-place safe).
// grid (mt=8, w=64, b=8), block 256 (4 waves). mt 0-3 -> a-side, 4-7 -> b-side.
__global__ __launch_bounds__(256) void agg_h_mfma(
    const u16* __restrict__ vTa, const u16* __restrict__ vTb,
    const u16* __restrict__ attb, u16* __restrict__ Pa, u16* __restrict__ Pb)
{
    __shared__ u16 Vs[128][72];  // [c][H'], rows 144 B (9x16B: aligned, 2-way banks)
    __shared__ u16 As[64][72];   // [h][H']
    const int mt = blockIdx.x, w = blockIdx.y, b = blockIdx.z;
    const u16* vT = (mt < 4) ? vTa : vTb;
    u16*       P  = (mt < 4) ? Pa  : Pb;
    const int c0 = (mt & 3) * 128;
    const int tid = threadIdx.x;
    const u16* va = vT + ((size_t)(b * 512 + c0) * 64 + w) * 64;          // + c*4096 + H'
    const u16* ab = attb + ((size_t)b * 4096 + w) * 128;                  // + h*8192 + H'
    // coalesced staging: 16B/thread, lanes 0-7 cover one contiguous 128B row
    {
        const int r = tid >> 3, cB = (tid & 7) * 8;
        #pragma unroll
        for (int i = 0; i < 4; i++)
            *(uint4*)&Vs[r + 32 * i][cB] = *(const uint4*)(va + (size_t)(r + 32 * i) * 4096 + cB);
        #pragma unroll
        for (int i = 0; i < 2; i++)
            *(uint4*)&As[r + 32 * i][cB] = *(const uint4*)(ab + (size_t)(r + 32 * i) * 8192 + cB);
    }
    __syncthreads();
    const int lane = tid & 63, wv = tid >> 6;
    const int wm = (wv & 1) * 64, wn = (wv >> 1) * 32;
    const int lr = lane & 15, lq = lane >> 4;
    f32x4 acc[4][2] = {};
    #pragma unroll
    for (int kt = 0; kt < 2; kt++) {
        const int k0 = kt * 32 + lq * 8;
        bf16x8 afr[4], bfr[2];
        #pragma unroll
        for (int i = 0; i < 4; i++) afr[i] = *(const bf16x8*)&Vs[wm + i * 16 + lr][k0];
        #pragma unroll
        for (int j = 0; j < 2; j++) bfr[j] = *(const bf16x8*)&As[wn + j * 16 + lr][k0];
        #pragma unroll
        for (int j = 0; j < 2; j++)
            #pragma unroll
            for (int i = 0; i < 4; i++)
                acc[i][j] = __builtin_amdgcn_mfma_f32_16x16x32_bf16(afr[i], bfr[j], acc[i][j], 0, 0, 0);
    }
    // D: row(c within 16-tile) = lq*4+r, col(h) = lr
    #pragma unroll
    for (int i = 0; i < 4; i++)
        #pragma unroll
        for (int j = 0; j < 2; j++) {
            u16* pp = P + ((size_t)(b * 512 + c0 + wm + i * 16 + lq * 4) * 64 + w) * 64 + wn + j * 16 + lr;
            #pragma unroll
            for (int r = 0; r < 4; r++) pp[(size_t)r * 4096] = f2bu(acc[i][j][r]);
        }
}

// ======================= W-aggregation (MFMA, LDS-staged) + epilogue ======
// OutW[c,w] (fixed b,h) = sum_W' v[b,c,h,W'] * attW[b,h,w,W']
// y = g*(P + OutW) + x   (P now in (b,c,h,w) bf16, x/y f32)
__global__ __launch_bounds__(256) void agg_w_mfma(
    const u16* __restrict__ v2, const u16* __restrict__ v1,
    const u16* __restrict__ P2, const u16* __restrict__ P1,
    const u16* __restrict__ attb,
    const float* __restrict__ x2, const float* __restrict__ x1,
    const float* __restrict__ gptr, float* __restrict__ out)
{
    __shared__ u16 Vs[128][72];  // [c][W']
    __shared__ u16 As[64][72];   // [w][W']
    const int mt = blockIdx.x, h = blockIdx.y, b = blockIdx.z;
    const u16* v = (mt < 4) ? v2 : v1;
    const u16* P = (mt < 4) ? P2 : P1;
    const float* x = (mt < 4) ? x2 : x1;
    float* y = out + ((mt < 4) ? 0 : PLANE);
    const int c0 = (mt & 3) * 128;
    const int tid = threadIdx.x;
    const u16* vb = v + (size_t)(b * 512 + c0) * 4096 + h * 64;           // + c*4096 + W'
    const u16* ab = attb + ((size_t)(b * 64 + h) * 64) * 128 + 64;        // + w*128 + W'
    {
        const int r = tid >> 3, cB = (tid & 7) * 8;
        #pragma unroll
        for (int i = 0; i < 4; i++)
            *(uint4*)&Vs[r + 32 * i][cB] = *(const uint4*)(vb + (size_t)(r + 32 * i) * 4096 + cB);
        #pragma unroll
        for (int i = 0; i < 2; i++)
            *(uint4*)&As[r + 32 * i][cB] = *(const uint4*)(ab + (size_t)(r + 32 * i) * 128 + cB);
    }
    __syncthreads();
    const int lane = tid & 63, wv = tid >> 6;
    const int wm = (wv & 1) * 64, wn = (wv >> 1) * 32;
    const int lr = lane & 15, lq = lane >> 4;
    f32x4 acc[4][2] = {};
    #pragma unroll
    for (int kt = 0; kt < 2; kt++) {
        const int k0 = kt * 32 + lq * 8;
        bf16x8 afr[4], bfr[2];
        #pragma unroll
        for (int i = 0; i < 4; i++) afr[i] = *(const bf16x8*)&Vs[wm + i * 16 + lr][k0];
        #pragma unroll
        for (int j = 0; j < 2; j++) bfr[j] = *(const bf16x8*)&As[wn + j * 16 + lr][k0];
        #pragma unroll
        for (int j = 0; j < 2; j++)
            #pragma unroll
            for (int i = 0; i < 4; i++)
                acc[i][j] = __builtin_amdgcn_mfma_f32_16x16x32_bf16(afr[i], bfr[j], acc[i][j], 0, 0, 0);
    }
    const float g = gptr[0];
    #pragma unroll
    for (int i = 0; i < 4; i++)
        #pragma unroll
        for (int j = 0; j < 2; j++) {
            size_t off = (size_t)(b * 512 + c0 + wm + i * 16 + lq * 4) * 4096
                       + (size_t)h * 64 + wn + j * 16 + lr;
            #pragma unroll
            for (int r = 0; r < 4; r++) {
                size_t o = off + (size_t)r * 4096;
                y[o] = g * (bfu2f(P[o]) + acc[i][j][r]) + x[o];
            }
        }
}

// ======================= host =======================
extern "C" void kernel_launch(void* const* d_in, const int* in_sizes, int n_in,
                              void* d_out, int out_size, void* d_ws, size_t ws_size,
                              hipStream_t stream)
{
    (void)in_sizes; (void)n_in; (void)out_size; (void)ws_size;
    const float* x2  = (const float*)d_in[0];
    const float* x1  = (const float*)d_in[1];
    const float* q_w = (const float*)d_in[2];
    const float* q_b = (const float*)d_in[3];
    const float* k_w = (const float*)d_in[4];
    const float* k_b = (const float*)d_in[5];
    const float* v_w = (const float*)d_in[6];
    const float* v_b = (const float*)d_in[7];
    const float* gm  = (const float*)d_in[8];

    // ws (MiB): v2 0-32 | v1 32-64 | attb 64-72 |
    //   scratch (dead after softmax): q 72-76 | k 76-80 | qT 80-84 | kT 84-88 | e 88-104
    //   vT2/P2 72-104, vT1/P1 104-136 (written after softmax; overlay scratch)
    // Total: 136 MiB.
    char* ws = (char*)d_ws;
    u16*   v2   = (u16*)(ws);
    u16*   v1   = (u16*)(ws + ((size_t)32  << 20));
    u16*   attb = (u16*)(ws + ((size_t)64  << 20));
    u16*   q    = (u16*)(ws + ((size_t)72  << 20));
    u16*   k    = (u16*)(ws + ((size_t)76  << 20));
    u16*   qT   = (u16*)(ws + ((size_t)80  << 20));
    u16*   kT   = (u16*)(ws + ((size_t)84  << 20));
    float* e    = (float*)(ws + ((size_t)88 << 20));
    u16*   vT2  = (u16*)(ws + ((size_t)72  << 20));  // overlays q..e (dead by then)
    u16*   vT1  = (u16*)(ws + ((size_t)104 << 20));
    float* out = (float*)d_out;

    dim3 blk(256);
    // fused q/k/v2 projection from x2 (M=640), v1 from x1 (M=512)
    proj_mfma<<<dim3(256, 5), blk, 0, stream>>>(x2, q_w, q_b, 64, k_w, k_b, 64,
                                                v_w, v_b, q, k, v2, 64, 64, 512);
    proj_mfma<<<dim3(256, 4), blk, 0, stream>>>(x1, v_w, v_b, 0, v_w, v_b, 0,
                                                v_w, v_b, q, k, v1, 64, 64, 512);
    transpose64_bb<<<1024, blk, 0, stream>>>(q, qT);        // q+k -> qT+kT
    energy_h<<<dim3(64, 8), blk, 0, stream>>>(qT, kT, e);
    energy_w<<<dim3(64, 8), blk, 0, stream>>>(q, k, e);
    softmax128_bf<<<8192, blk, 0, stream>>>(e, attb);       // e dead after this
    transpose64_bb<<<8192, blk, 0, stream>>>(v2, vT2);      // v2+v1 -> vT2+vT1
    agg_h_mfma<<<dim3(8, 64, 8), blk, 0, stream>>>(vT2, vT1, attb, vT2, vT1); // P over vT
    transpose64_bb_inplace<<<8192, blk, 0, stream>>>(vT2);  // P -> (b,c,h,w)
    agg_w_mfma<<<dim3(8, 64, 8), blk, 0, stream>>>(v2, v1, vT2, vT1, attb,
                                                   x2, x1, gm, out);
}